// Round 1
// baseline (685.644 us; speedup 1.0000x reference)
//
#include <hip/hip_runtime.h>
#include <math.h>

#define HIDDEN  512
#define INPUT   8
#define NUM_MIX 2
#define BATCH   64
#define SEQ     2048
#define DD      12
#define KOUT    10
#define TTILE   16
#define NTILES  (SEQ/TTILE)

// h-state kept pre-scaled by 2*log2(e): tanh(h) = 1 - 2*rcp(exp2(h_s)+1)
#define SCALE_F 2.8853900817779268
#define AB_F    0.09765625f   /* alpha*BASE_SCALE/HIDDEN = 50/512 */
#define C1_F    0.6931471805599453f   /* ln2 */
#define C2_F    0.2402265069591007f   /* ln2^2 / 2 */

typedef float v2f __attribute__((ext_vector_type(2)));
typedef float f4v __attribute__((ext_vector_type(4)));
typedef unsigned int v2u __attribute__((ext_vector_type(2)));

__device__ __forceinline__ v2f pk_fma(v2f a, v2f b, v2f c) {
    return __builtin_elementwise_fma(a, b, c);
}

template<int CTRL>
__device__ __forceinline__ float dpp_add(float x) {
    int y = __builtin_amdgcn_update_dpp(0, __float_as_int(x), CTRL, 0xF, 0xF, true);
    return x + __int_as_float(y);
}
__device__ __forceinline__ float wave_allsum(float x) {
    x = dpp_add<0x111>(x);   // row_shr:1
    x = dpp_add<0x112>(x);   // row_shr:2
    x = dpp_add<0x114>(x);   // row_shr:4
    x = dpp_add<0x118>(x);   // row_shr:8
    x = dpp_add<0x142>(x);   // row_bcast:15
    x = dpp_add<0x143>(x);   // row_bcast:31
    return __int_as_float(__builtin_amdgcn_readlane(__float_as_int(x), 63));
}

// Fused dual reduction: v0 = sum64(p0), v1 = sum64(p1).
__device__ __forceinline__ void allsum2(float p0, float p1,
                                        float& v0, float& v1) {
#if __has_builtin(__builtin_amdgcn_permlane32_swap)
    v2u sw = __builtin_amdgcn_permlane32_swap(
        __float_as_uint(p0), __float_as_uint(p1), false, false);
    float z = __uint_as_float(sw.x) + __uint_as_float(sw.y);
    z = dpp_add<0x111>(z);   // row_shr:1
    z = dpp_add<0x112>(z);   // row_shr:2
    z = dpp_add<0x114>(z);   // row_shr:4
    z = dpp_add<0x118>(z);   // row_shr:8  -> lane15/31/47/63 = row sums
    z = dpp_add<0x142>(z);   // row_bcast:15 -> lane31 = S0, lane63 = S1
    v0 = __int_as_float(__builtin_amdgcn_readlane(__float_as_int(z), 31));
    v1 = __int_as_float(__builtin_amdgcn_readlane(__float_as_int(z), 63));
#else
    v0 = wave_allsum(p0);
    v1 = wave_allsum(p1);
#endif
}

__global__ __launch_bounds__(256) void fsm_rnn_kernel(
    const float* __restrict__ x,          // (B, SEQ, INPUT)
    const float* __restrict__ means,      // (NUM_MIX, DD)
    const float* __restrict__ scale_tril, // (NUM_MIX, DD, DD)
    const float* __restrict__ mixw,       // (NUM_MIX,)
    const float* __restrict__ seeds,      // (4, HIDDEN, DD)
    const int*   __restrict__ cur_seeds,  // (B,)
    float*       __restrict__ out)        // (B, SEQ, KOUT)
{
    // IxP pair-layout: [dbuf][tt][q][lane][pr] holds unit h = lane + 64*(2q+pr)
    __shared__ __align__(16) float IxP[2][TTILE][4][64][2];  // 64KB
    __shared__ __align__(16) float xsB[2][TTILE*INPUT];      // 1KB raw x tiles
    __shared__ __align__(16) float IvL[HIDDEN][INPUT];       // 16KB alpha*I (scaled)
    __shared__ float PM0[HIDDEN], PM1[HIDDEN], N0[HIDDEN], N1[HIDDEN]; // 8KB
    __shared__ __align__(8) float vr2[2][TTILE][64][2];      // 16KB per-lane v copies
    __shared__ double Leff[DD*DD];
    __shared__ double meansw[DD];

    const int tid  = threadIdx.x;
    const int lane = tid & 63;
    const int wid  = tid >> 6;
    const int b    = blockIdx.x;
    const int s    = cur_seeds[b];
    const float* xb = x + (size_t)b * SEQ * INPUT;
    float* outb = out + (size_t)b * SEQ * KOUT;

    // ---- mixture weights ----
    double w0 = fmax((double)mixw[0], 1e-6);
    double w1 = fmax((double)mixw[1], 1e-6);
    double wsum = w0 + w1; w0 /= wsum; w1 /= wsum;

    // ---- weighted clamped-tril L, weighted means ----
    if (tid < DD*DD) {
        int d = tid / DD, e = tid % DD;
        double acc = 0.0;
        #pragma unroll
        for (int i = 0; i < NUM_MIX; ++i) {
            float v = scale_tril[i*DD*DD + d*DD + e];
            float c = (d > e) ? v : (d == e ? fabsf(v - 1e-12f) + 1e-12f : 0.0f);
            acc += (i == 0 ? w0 : w1) * (double)c;
        }
        Leff[tid] = acc;
    }
    if (tid < DD)
        meansw[tid] = w0 * (double)means[tid] + w1 * (double)means[DD + tid];
    if (tid < 2*TTILE*INPUT)
        ((float*)xsB)[tid] = xb[tid];          // stage x tiles 0,1
    __syncthreads();

    // ---- per-h params (double), stored pre-scaled ----
    #pragma unroll
    for (int rr = 0; rr < 2; ++rr) {
        int h = tid + rr*256;
        const float* sh = &seeds[(s*HIDDEN + h)*DD];
        double comb[DD];
        #pragma unroll
        for (int d = 0; d < DD; ++d) {
            double acc = meansw[d];
            for (int e = 0; e <= d; ++e)
                acc += Leff[d*DD + e] * (double)sh[e];
            comb[d] = acc;
        }
        PM0[h] = (float)(SCALE_F * (double)AB_F * comb[0]);
        PM1[h] = (float)(SCALE_F * (double)AB_F * comb[1]);
        N0[h]  = (float)comb[2];
        N1[h]  = (float)comb[3];
        #pragma unroll
        for (int i = 0; i < INPUT; ++i)
            IvL[h][i] = (float)(SCALE_F * 0.1 * comb[4 + i]);
    }
    __syncthreads();

    // ---- persistent per-role state ----
    // Consumer pipeline: tanh(h_t) = 1 - 2*R_t, R_t = Rpre*1/(1+eps),
    //   Epre = exp2(hc), Rpre = 1/(Epre+1), Ppre = Epre*Rpre  (off-chain)
    //   eps  = (2^delta - 1)*Ppre,  delta = AM0*v0 + AM1*v1 + DBIAS (on-chain)
    // Dot weights pre-scaled: W = -2*N*Rpre; v_full = v' + sum(N).
    v2f AM0[4], AM1[4], NN0m2[4], NN1m2[4], DB[4];
    v2f hc[4], Ppre[4], W0[4], W1[4];
    float v0p = 0.0f, v1p = 0.0f, sum0 = 0.0f, sum1 = 0.0f;
    f4v IvA[3], IvC[3];
    float zf = 0.0f, wst = 0.0f;
    const int pid = (wid - 1)*64 + lane;   // producer id 0..191
    const int zi  = lane - 56;

    if (wid == 0) {
        float ps0 = 0.0f, ps1 = 0.0f;
        #pragma unroll
        for (int q = 0; q < 4; ++q) {
            int ha = lane + 128*q, hb = ha + 64;
            AM0[q] = (v2f){PM0[ha], PM0[hb]};
            AM1[q] = (v2f){PM1[ha], PM1[hb]};
            float n0a = N0[ha], n0b = N0[hb];
            float n1a = N1[ha], n1b = N1[hb];
            NN0m2[q] = (v2f){-2.0f*n0a, -2.0f*n0b};
            NN1m2[q] = (v2f){-2.0f*n1a, -2.0f*n1b};
            // priming: hc = 0 -> Epre = 1, Rpre = 0.5, Ppre = 0.5, W = -N
            W0[q]   = (v2f){-n0a, -n0b};
            W1[q]   = (v2f){-n1a, -n1b};
            Ppre[q] = (v2f){0.5f, 0.5f};
            hc[q]   = (v2f){0.0f, 0.0f};
            ps0 += n0a + n0b;
            ps1 += n1a + n1b;
        }
        allsum2(ps0, ps1, sum0, sum1);
        #pragma unroll
        for (int q = 0; q < 4; ++q) {
            DB[q].x = fmaf(AM0[q].x, sum0, AM1[q].x * sum1);
            DB[q].y = fmaf(AM0[q].y, sum0, AM1[q].y * sum1);
        }
        // priming: delta_{-1} = DB + AM0*(-sum0) + AM1*(-sum1) = 0 exactly
        v0p = -sum0; v1p = -sum1;
    } else {
        #pragma unroll
        for (int q = 0; q < 3; ++q) {
            int h = pid + 192*q;
            if (h < HIDDEN) {
                IvA[q] = *(const f4v*)&IvL[h][0];
                IvC[q] = *(const f4v*)&IvL[h][4];
            }
        }
    }

    // producer: fill IxP tile tg; wave1 lanes 56-63 emit the z-filter outputs
    auto produce = [&](int tg) {
        const int pb = tg & 1;
        const float* xs = xsB[pb];
        for (int tt = 0; tt < TTILE; ++tt) {
            f4v xa = *(const f4v*)&xs[tt*INPUT];
            f4v xc = *(const f4v*)&xs[tt*INPUT + 4];
            #pragma unroll
            for (int q = 0; q < 3; ++q) {
                int h = pid + 192*q;
                if (h < HIDDEN) {
                    float v =      IvA[q].x * xa.x;
                    v = fmaf(IvA[q].y, xa.y, v);
                    v = fmaf(IvA[q].z, xa.z, v);
                    v = fmaf(IvA[q].w, xa.w, v);
                    v = fmaf(IvC[q].x, xc.x, v);
                    v = fmaf(IvC[q].y, xc.y, v);
                    v = fmaf(IvC[q].z, xc.z, v);
                    v = fmaf(IvC[q].w, xc.w, v);
                    IxP[pb][tt][(h >> 7)][h & 63][(h >> 6) & 1] = v;
                }
            }
        }
        if (wid == 1 && lane >= 56) {
            #pragma unroll 4
            for (int tt = 0; tt < TTILE; ++tt) {
                zf = fmaf(0.9f, zf, 0.1f * xs[tt*INPUT + zi]);
                outb[(tg*TTILE + tt)*KOUT + 2 + zi] = zf;
            }
        }
    };

    // w-EMA for cols 0,1 (wave 1, lanes 54,55) — reads lane 0's v copy
    auto process_w = [&](int tile) {
        if (lane == 54 || lane == 55) {
            const int widx = lane & 1;
            for (int tt = 0; tt < TTILE; ++tt) {
                wst = fmaf(0.9f, wst, AB_F * vr2[tile & 1][tt][0][widx]);
                outb[(tile*TTILE + tt)*KOUT + widx] = wst;
            }
        }
    };

    if (wid != 0) produce(0);
    __syncthreads();

    for (int T = 0; T < NTILES; ++T) {
        if (wid == 0) {
            const int pb = T & 1;
            v2f CC[4], CN[4];
            #pragma unroll
            for (int q = 0; q < 4; ++q)
                CC[q] = *(const v2f*)&IxP[pb][0][q][lane][0];
            #pragma unroll 1
            for (int tt = 0; tt < TTILE; ++tt) {
                if (tt < TTILE-1) {            // b64 prefetch, 2-way banks = free
                    #pragma unroll
                    for (int q = 0; q < 4; ++q)
                        CN[q] = *(const v2f*)&IxP[pb][tt+1][q][lane][0];
                }
                // ==== CHAIN: delta (exact exp2-domain increment from v) ====
                v2f del[4];
                #pragma unroll
                for (int q = 0; q < 4; ++q) {
                    del[q].x = fmaf(AM0[q].x, v0p, fmaf(AM1[q].x, v1p, DB[q].x));
                    del[q].y = fmaf(AM0[q].y, v0p, fmaf(AM1[q].y, v1p, DB[q].y));
                }
                // ==== CHAIN: rc = 1/(1+eps), eps = (2^del - 1)*Ppre ====
                // |del| <~ 0.1: f1 = del*ln2 + (del*ln2)^2/2, rcp via 1-e+e^2
                v2f rc[4];
                #pragma unroll
                for (int q = 0; q < 4; ++q) {
                    v2f t  = pk_fma(del[q], (v2f){C2_F, C2_F}, (v2f){C1_F, C1_F});
                    v2f f1 = del[q] * t;
                    v2f ep = f1 * Ppre[q];
                    v2f em = ep - 1.0f;
                    rc[q]  = pk_fma(ep, em, (v2f){1.0f, 1.0f});
                }
                // ==== CHAIN: dot trees with this step's pre-scaled weights ====
                v2f a0 = W0[0]*rc[0]; a0 = pk_fma(W0[1], rc[1], a0);
                v2f b0 = W0[2]*rc[2]; b0 = pk_fma(W0[3], rc[3], b0);
                v2f a1 = W1[0]*rc[0]; a1 = pk_fma(W1[1], rc[1], a1);
                v2f b1 = W1[2]*rc[2]; b1 = pk_fma(W1[3], rc[3], b1);
                v2f s0 = a0 + b0, s1 = a1 + b1;
                float p0 = s0.x + s0.y;
                float p1 = s1.x + s1.y;

                // ==== OFF-CHAIN: advance exp/rcp pipeline for NEXT step ====
                // (depends only on del; a full step of slack — fills DPP/trans
                //  stall slots of the reduce below)
                v2f hcn[4], Pn[4], W0n[4], W1n[4];
                #pragma unroll
                for (int q = 0; q < 4; ++q) {
                    v2f Hn = hc[q] + del[q];                       // exact H_t
                    hcn[q] = pk_fma((v2f){0.9f,0.9f}, Hn, CC[q]);  // hc_t
                    v2f E, A, R;
                    E.x = __builtin_amdgcn_exp2f(hcn[q].x);
                    E.y = __builtin_amdgcn_exp2f(hcn[q].y);
                    A = E + 1.0f;
                    R.x = __builtin_amdgcn_rcpf(A.x);
                    R.y = __builtin_amdgcn_rcpf(A.y);
                    Pn[q]  = R * E;
                    W0n[q] = NN0m2[q] * R;
                    W1n[q] = NN1m2[q] * R;
                }

                // ==== CHAIN: fused dual wave reduction ====
                float v0n, v1n;
                allsum2(p0, p1, v0n, v1n);

                // unconditional per-lane copy of FULL v (v' + sum(N))
                *(v2f*)&vr2[pb][tt][lane][0] = (v2f){v0n + sum0, v1n + sum1};

                // commit pipeline state
                #pragma unroll
                for (int q = 0; q < 4; ++q) {
                    hc[q]   = hcn[q];
                    Ppre[q] = Pn[q];
                    W0[q]   = W0n[q];
                    W1[q]   = W1n[q];
                }
                if (tt < TTILE-1) {
                    #pragma unroll
                    for (int q = 0; q < 4; ++q) CC[q] = CN[q];
                }
                v0p = v0n; v1p = v1n;
            }
        } else {
            if (T + 1 < NTILES) produce(T + 1);
            if (wid == 2 && T + 2 < NTILES) {
                const int base = (T + 2)*(TTILE*INPUT);
                xsB[T & 1][lane]      = xb[base + lane];
                xsB[T & 1][lane + 64] = xb[base + lane + 64];
            }
            if (wid == 1 && T >= 1) process_w(T - 1);
        }
        __syncthreads();
    }
    if (wid == 1) process_w(NTILES - 1);
}

extern "C" void kernel_launch(void* const* d_in, const int* in_sizes, int n_in,
                              void* d_out, int out_size, void* d_ws, size_t ws_size,
                              hipStream_t stream) {
    (void)d_ws; (void)ws_size;
    const float* x          = (const float*)d_in[0];
    const float* means      = (const float*)d_in[1];
    const float* scale_tril = (const float*)d_in[2];
    const float* mixw       = (const float*)d_in[3];
    const float* seeds      = (const float*)d_in[4];
    const int*   cur_seeds  = (const int*)d_in[5];
    float* out = (float*)d_out;

    fsm_rnn_kernel<<<BATCH, 256, 0, stream>>>(
        x, means, scale_tril, mixw, seeds, cur_seeds, out);
}

// Round 3
// 530.119 us; speedup vs baseline: 1.2934x; 1.2934x over previous
//
#include <hip/hip_runtime.h>
#include <math.h>

#define HIDDEN  512
#define INPUT   8
#define NUM_MIX 2
#define BATCH   64
#define SEQ     2048
#define DD      12
#define KOUT    10
#define TTILE   16
#define NTILES  (SEQ/TTILE)

// h-state kept pre-scaled by 2*log2(e): tanh(h) = 1 - 2*rcp(exp2(h_s)+1)
#define SCALE_F 2.8853900817779268
#define AB_F    0.09765625f   /* alpha*BASE_SCALE/HIDDEN = 50/512 */
#define C1_F    0.6931471805599453f   /* ln2 */
#define C2_F    0.2402265069591007f   /* ln2^2 / 2 */

typedef float v2f __attribute__((ext_vector_type(2)));
typedef float f4v __attribute__((ext_vector_type(4)));
typedef unsigned int v2u __attribute__((ext_vector_type(2)));

__device__ __forceinline__ v2f pk_fma(v2f a, v2f b, v2f c) {
    return __builtin_elementwise_fma(a, b, c);
}

template<int CTRL>
__device__ __forceinline__ float dpp_add(float x) {
    int y = __builtin_amdgcn_update_dpp(0, __float_as_int(x), CTRL, 0xF, 0xF, true);
    return x + __int_as_float(y);
}
__device__ __forceinline__ float wave_allsum(float x) {
    x = dpp_add<0x111>(x);   // row_shr:1
    x = dpp_add<0x112>(x);   // row_shr:2
    x = dpp_add<0x114>(x);   // row_shr:4
    x = dpp_add<0x118>(x);   // row_shr:8
    x = dpp_add<0x142>(x);   // row_bcast:15
    x = dpp_add<0x143>(x);   // row_bcast:31
    return __int_as_float(__builtin_amdgcn_readlane(__float_as_int(x), 63));
}

// Fused dual reduction: v0 = sum64(p0), v1 = sum64(p1).
__device__ __forceinline__ void allsum2(float p0, float p1,
                                        float& v0, float& v1) {
#if __has_builtin(__builtin_amdgcn_permlane32_swap)
    v2u sw = __builtin_amdgcn_permlane32_swap(
        __float_as_uint(p0), __float_as_uint(p1), false, false);
    float z = __uint_as_float(sw.x) + __uint_as_float(sw.y);
    z = dpp_add<0x111>(z);   // row_shr:1
    z = dpp_add<0x112>(z);   // row_shr:2
    z = dpp_add<0x114>(z);   // row_shr:4
    z = dpp_add<0x118>(z);   // row_shr:8  -> lane15/31/47/63 = row sums
    z = dpp_add<0x142>(z);   // row_bcast:15 -> lane31 = S0, lane63 = S1
    v0 = __int_as_float(__builtin_amdgcn_readlane(__float_as_int(z), 31));
    v1 = __int_as_float(__builtin_amdgcn_readlane(__float_as_int(z), 63));
#else
    v0 = wave_allsum(p0);
    v1 = wave_allsum(p1);
#endif
}

__global__ __launch_bounds__(256) void fsm_rnn_kernel(
    const float* __restrict__ x,          // (B, SEQ, INPUT)
    const float* __restrict__ means,      // (NUM_MIX, DD)
    const float* __restrict__ scale_tril, // (NUM_MIX, DD, DD)
    const float* __restrict__ mixw,       // (NUM_MIX,)
    const float* __restrict__ seeds,      // (4, HIDDEN, DD)
    const int*   __restrict__ cur_seeds,  // (B,)
    float*       __restrict__ out)        // (B, SEQ, KOUT)
{
    // IxP pair-layout: [dbuf][tt][q][lane][pr] holds unit h = lane + 64*(2q+pr)
    __shared__ __align__(16) float IxP[2][TTILE][4][64][2];  // 64KB
    __shared__ __align__(16) float xsB[2][TTILE*INPUT];      // 1KB raw x tiles
    __shared__ __align__(16) float IvL[HIDDEN][INPUT];       // 16KB alpha*I (scaled)
    __shared__ float PM0[HIDDEN], PM1[HIDDEN], N0[HIDDEN], N1[HIDDEN]; // 8KB
    __shared__ __align__(8) float vr2[2][TTILE][64][2];      // 16KB per-lane v copies
    __shared__ double Leff[DD*DD];
    __shared__ double meansw[DD];

    const int tid  = threadIdx.x;
    const int lane = tid & 63;
    const int wid  = tid >> 6;
    const int b    = blockIdx.x;
    const int s    = cur_seeds[b];
    const float* xb = x + (size_t)b * SEQ * INPUT;
    float* outb = out + (size_t)b * SEQ * KOUT;

    // ---- mixture weights ----
    double w0 = fmax((double)mixw[0], 1e-6);
    double w1 = fmax((double)mixw[1], 1e-6);
    double wsum = w0 + w1; w0 /= wsum; w1 /= wsum;

    // ---- weighted clamped-tril L, weighted means ----
    if (tid < DD*DD) {
        int d = tid / DD, e = tid % DD;
        double acc = 0.0;
        #pragma unroll
        for (int i = 0; i < NUM_MIX; ++i) {
            float v = scale_tril[i*DD*DD + d*DD + e];
            float c = (d > e) ? v : (d == e ? fabsf(v - 1e-12f) + 1e-12f : 0.0f);
            acc += (i == 0 ? w0 : w1) * (double)c;
        }
        Leff[tid] = acc;
    }
    if (tid < DD)
        meansw[tid] = w0 * (double)means[tid] + w1 * (double)means[DD + tid];
    if (tid < 2*TTILE*INPUT)
        ((float*)xsB)[tid] = xb[tid];          // stage x tiles 0,1
    __syncthreads();

    // ---- per-h params (double), stored pre-scaled ----
    #pragma unroll
    for (int rr = 0; rr < 2; ++rr) {
        int h = tid + rr*256;
        const float* sh = &seeds[(s*HIDDEN + h)*DD];
        double comb[DD];
        #pragma unroll
        for (int d = 0; d < DD; ++d) {
            double acc = meansw[d];
            for (int e = 0; e <= d; ++e)
                acc += Leff[d*DD + e] * (double)sh[e];
            comb[d] = acc;
        }
        PM0[h] = (float)(SCALE_F * (double)AB_F * comb[0]);
        PM1[h] = (float)(SCALE_F * (double)AB_F * comb[1]);
        N0[h]  = (float)comb[2];
        N1[h]  = (float)comb[3];
        #pragma unroll
        for (int i = 0; i < INPUT; ++i)
            IvL[h][i] = (float)(SCALE_F * 0.1 * comb[4 + i]);
    }
    __syncthreads();

    // ---- persistent per-role state ----
    // Consumer pipeline (algebraic tanh split):
    //   tanh(H) = 1 - 2*R,  R = Rpre/(1+eps)
    //   Epre = exp2(hc), Rpre = 1/(Epre+1), Ppre = Epre*Rpre   [off-chain]
    //   eps  = (2^del - 1)*Ppre, del = AM0*v0' + AM1*v1' + DB  [on-chain]
    // Invariant entering step t: hc = 0.9*H[t-2] + CC[t-1]; H[t-1] = hc+del_t.
    // Dot weights pre-scaled: W = -2*N*Rpre; v_full = v' + sum(N).
    v2f AM0[4], AM1[4], NN0m2[4], NN1m2[4], DB[4];
    v2f hc[4], Ppre[4], W0[4], W1[4];
    float v0p = 0.0f, v1p = 0.0f, sum0 = 0.0f, sum1 = 0.0f;
    f4v IvA[3], IvC[3];
    float zf = 0.0f, wst = 0.0f;
    const int pid = (wid - 1)*64 + lane;   // producer id 0..191
    const int zi  = lane - 56;

    if (wid == 0) {
        float ps0 = 0.0f, ps1 = 0.0f;
        #pragma unroll
        for (int q = 0; q < 4; ++q) {
            int ha = lane + 128*q, hb = ha + 64;
            AM0[q] = (v2f){PM0[ha], PM0[hb]};
            AM1[q] = (v2f){PM1[ha], PM1[hb]};
            float n0a = N0[ha], n0b = N0[hb];
            float n1a = N1[ha], n1b = N1[hb];
            NN0m2[q] = (v2f){-2.0f*n0a, -2.0f*n0b};
            NN1m2[q] = (v2f){-2.0f*n1a, -2.0f*n1b};
            // priming: hc = 0 -> Epre = 1, Rpre = 0.5, Ppre = 0.5, W = -N
            W0[q]   = (v2f){-n0a, -n0b};
            W1[q]   = (v2f){-n1a, -n1b};
            Ppre[q] = (v2f){0.5f, 0.5f};
            hc[q]   = (v2f){0.0f, 0.0f};
            ps0 += n0a + n0b;
            ps1 += n1a + n1b;
        }
        allsum2(ps0, ps1, sum0, sum1);
        #pragma unroll
        for (int q = 0; q < 4; ++q) {
            DB[q].x = fmaf(AM0[q].x, sum0, AM1[q].x * sum1);
            DB[q].y = fmaf(AM0[q].y, sum0, AM1[q].y * sum1);
        }
        // priming: del_0 = DB + AM0*(-sum0) + AM1*(-sum1) = 0 exactly
        v0p = -sum0; v1p = -sum1;
    } else {
        #pragma unroll
        for (int q = 0; q < 3; ++q) {
            int h = pid + 192*q;
            if (h < HIDDEN) {
                IvA[q] = *(const f4v*)&IvL[h][0];
                IvC[q] = *(const f4v*)&IvL[h][4];
            }
        }
    }

    // producer: fill IxP tile tg; wave1 lanes 56-63 emit the z-filter outputs
    auto produce = [&](int tg) {
        const int pb = tg & 1;
        const float* xs = xsB[pb];
        for (int tt = 0; tt < TTILE; ++tt) {
            f4v xa = *(const f4v*)&xs[tt*INPUT];
            f4v xc = *(const f4v*)&xs[tt*INPUT + 4];
            #pragma unroll
            for (int q = 0; q < 3; ++q) {
                int h = pid + 192*q;
                if (h < HIDDEN) {
                    float v =      IvA[q].x * xa.x;
                    v = fmaf(IvA[q].y, xa.y, v);
                    v = fmaf(IvA[q].z, xa.z, v);
                    v = fmaf(IvA[q].w, xa.w, v);
                    v = fmaf(IvC[q].x, xc.x, v);
                    v = fmaf(IvC[q].y, xc.y, v);
                    v = fmaf(IvC[q].z, xc.z, v);
                    v = fmaf(IvC[q].w, xc.w, v);
                    IxP[pb][tt][(h >> 7)][h & 63][(h >> 6) & 1] = v;
                }
            }
        }
        if (wid == 1 && lane >= 56) {
            #pragma unroll 4
            for (int tt = 0; tt < TTILE; ++tt) {
                zf = fmaf(0.9f, zf, 0.1f * xs[tt*INPUT + zi]);
                outb[(tg*TTILE + tt)*KOUT + 2 + zi] = zf;
            }
        }
    };

    // w-EMA for cols 0,1 (wave 1, lanes 54,55) — reads lane 0's v copy
    auto process_w = [&](int tile) {
        if (lane == 54 || lane == 55) {
            const int widx = lane & 1;
            for (int tt = 0; tt < TTILE; ++tt) {
                wst = fmaf(0.9f, wst, AB_F * vr2[tile & 1][tt][0][widx]);
                outb[(tile*TTILE + tt)*KOUT + widx] = wst;
            }
        }
    };

    if (wid != 0) produce(0);
    __syncthreads();

    for (int T = 0; T < NTILES; ++T) {
        if (wid == 0) {
            const int pb = T & 1;
            v2f CC[4], CN[4];
            #pragma unroll
            for (int q = 0; q < 4; ++q)
                CC[q] = *(const v2f*)&IxP[pb][0][q][lane][0];
            #pragma unroll
            for (int tt = 0; tt < TTILE; ++tt) {
                if (tt < TTILE-1) {            // b64 prefetch, 2-way banks = free
                    #pragma unroll
                    for (int q = 0; q < 4; ++q)
                        CN[q] = *(const v2f*)&IxP[pb][tt+1][q][lane][0];
                }
                // ==== CHAIN: del (exact exp2-domain increment), packed ====
                v2f v0v = {v0p, v0p}, v1v = {v1p, v1p};
                v2f del[4];
                #pragma unroll
                for (int q = 0; q < 4; ++q)
                    del[q] = pk_fma(AM0[q], v0v, pk_fma(AM1[q], v1v, DB[q]));
                // ==== CHAIN: rc = 1/(1+eps), eps = (2^del - 1)*Ppre ====
                // |del| small: f1 = del*ln2 + (del*ln2)^2/2; rcp via 1-e+e^2
                v2f rc[4];
                #pragma unroll
                for (int q = 0; q < 4; ++q) {
                    v2f t  = pk_fma(del[q], (v2f){C2_F, C2_F}, (v2f){C1_F, C1_F});
                    v2f f1 = del[q] * t;
                    v2f ep = f1 * Ppre[q];
                    v2f em = ep - 1.0f;
                    rc[q]  = pk_fma(ep, em, (v2f){1.0f, 1.0f});
                }
                // ==== CHAIN: dot trees with pre-scaled weights ====
                v2f a0 = W0[0]*rc[0]; a0 = pk_fma(W0[1], rc[1], a0);
                v2f b0 = W0[2]*rc[2]; b0 = pk_fma(W0[3], rc[3], b0);
                v2f a1 = W1[0]*rc[0]; a1 = pk_fma(W1[1], rc[1], a1);
                v2f b1 = W1[2]*rc[2]; b1 = pk_fma(W1[3], rc[3], b1);
                v2f s0 = a0 + b0, s1 = a1 + b1;
                float p0 = s0.x + s0.y;
                float p1 = s1.x + s1.y;

                // ==== OFF-CHAIN: advance exp/rcp pipeline for NEXT step ====
                // (depends only on del; a full step of slack — fills the DPP
                //  reduce bubble below; fully-unrolled loop -> SSA renames)
                #pragma unroll
                for (int q = 0; q < 4; ++q) {
                    v2f Hn  = hc[q] + del[q];                       // exact H_t
                    v2f hcn = pk_fma((v2f){0.9f,0.9f}, Hn, CC[q]);  // hc_t
                    v2f E, A, R;
                    E.x = __builtin_amdgcn_exp2f(hcn.x);
                    E.y = __builtin_amdgcn_exp2f(hcn.y);
                    A = E + 1.0f;
                    R.x = __builtin_amdgcn_rcpf(A.x);
                    R.y = __builtin_amdgcn_rcpf(A.y);
                    hc[q]   = hcn;
                    Ppre[q] = R * E;
                    W0[q]   = NN0m2[q] * R;
                    W1[q]   = NN1m2[q] * R;
                }

                // ==== CHAIN: fused dual wave reduction ====
                float v0n, v1n;
                allsum2(p0, p1, v0n, v1n);

                // unconditional per-lane copy of FULL v (v' + sum(N))
                *(v2f*)&vr2[pb][tt][lane][0] = (v2f){v0n + sum0, v1n + sum1};

                if (tt < TTILE-1) {
                    #pragma unroll
                    for (int q = 0; q < 4; ++q) CC[q] = CN[q];
                }
                v0p = v0n; v1p = v1n;
            }
        } else {
            if (T + 1 < NTILES) produce(T + 1);
            if (wid == 2 && T + 2 < NTILES) {
                const int base = (T + 2)*(TTILE*INPUT);
                xsB[T & 1][lane]      = xb[base + lane];
                xsB[T & 1][lane + 64] = xb[base + lane + 64];
            }
            if (wid == 1 && T >= 1) process_w(T - 1);
        }
        __syncthreads();
    }
    if (wid == 1) process_w(NTILES - 1);
}

extern "C" void kernel_launch(void* const* d_in, const int* in_sizes, int n_in,
                              void* d_out, int out_size, void* d_ws, size_t ws_size,
                              hipStream_t stream) {
    (void)d_ws; (void)ws_size;
    const float* x          = (const float*)d_in[0];
    const float* means      = (const float*)d_in[1];
    const float* scale_tril = (const float*)d_in[2];
    const float* mixw       = (const float*)d_in[3];
    const float* seeds      = (const float*)d_in[4];
    const int*   cur_seeds  = (const int*)d_in[5];
    float* out = (float*)d_out;

    fsm_rnn_kernel<<<BATCH, 256, 0, stream>>>(
        x, means, scale_tril, mixw, seeds, cur_seeds, out);
}